// Round 1
// baseline (608.194 us; speedup 1.0000x reference)
//
#include <hip/hip_runtime.h>

// Sparse deconv (27-tap) + BN + ReLU for MI355X.
// Strategy: invert the per-offset scatter (out_idx unique within an offset)
// into a dense gather map src[k][dst] in ws, then accumulate per 128-row tile
// in LDS with per-offset weight staging. No output atomics. BN stats via
// 96-channel global atomics, then fused normalize+ReLU in-place in d_out.

#define N_VOX 200000
#define INC   64
#define OUTC  96
#define NOFF  26
#define ROWS  128
#define EPSV  1e-5f

__global__ void init_ws_kernel(int* __restrict__ srcmap, float* __restrict__ stats) {
    int idx = blockIdx.x * blockDim.x + threadIdx.x;
    int stride = gridDim.x * blockDim.x;
    for (int i = idx; i < NOFF * N_VOX; i += stride) srcmap[i] = -1;
    if (idx < 4 * OUTC) stats[idx] = 0.0f;
}

__global__ void fill_src_kernel(const int* __restrict__ in_idx,
                                const int* __restrict__ out_idx,
                                int P, int* __restrict__ srcmap) {
    int idx = blockIdx.x * blockDim.x + threadIdx.x;
    if (idx >= NOFF * P) return;
    int dst = out_idx[idx];
    if (dst >= N_VOX) return;            // padded sink entries
    int k = idx / P;
    srcmap[k * N_VOX + dst] = in_idx[idx];
}

__global__ __launch_bounds__(256, 2)
void conv_kernel(const float* __restrict__ feats,
                 const float* __restrict__ Wc,
                 const float* __restrict__ Woff,
                 const int* __restrict__ srcmap,
                 float* __restrict__ out,
                 float* __restrict__ stats) {
    __shared__ __align__(16) float Wlds[INC * OUTC];   // 24.6 KB
    __shared__ __align__(16) float acc[ROWS * OUTC];   // 49.2 KB
    __shared__ float flds[4][2][INC];                  // 2 KB
    __shared__ int lr[ROWS];
    __shared__ int ls[ROWS];
    __shared__ int cnt;

    const int t    = threadIdx.x;
    const int wid  = t >> 6;
    const int lane = t & 63;
    const int base = blockIdx.x * ROWS;

    // lane -> (row-half, channel quad): lanes 0..23 row A, 24..47 row B, 48..63 idle
    const int half = lane / 24;          // 0,1 compute; 2 idle
    const int cq   = (lane % 24) * 4;

    for (int i = t; i < ROWS * OUTC; i += 256) acc[i] = 0.0f;

    for (int m = 0; m < 27; ++m) {
        __syncthreads();  // protect Wlds/lists/acc from previous offset
        const float* __restrict__ Wsrc = (m == 26) ? Wc : (Woff + m * (INC * OUTC));
        for (int i = t; i < INC * OUTC; i += 256) Wlds[i] = Wsrc[i];
        if (t == 0) cnt = 0;
        __syncthreads();

        // compact rows active under this offset (dst unique per offset -> r unique)
        if (t < ROWS) {
            int row = base + t;
            if (row < N_VOX) {
                int s = (m == 26) ? row : srcmap[m * N_VOX + row];
                if (s >= 0) {
                    int p = atomicAdd(&cnt, 1);
                    lr[p] = t;
                    ls[p] = s;
                }
            }
        }
        __syncthreads();

        const int ce = cnt;
        for (int e = wid * 2; e < ce; e += 8) {
            const bool has1 = (e + 1) < ce;
            const int e1 = has1 ? (e + 1) : e;
            const int s0 = ls[e], s1 = ls[e1];
            // stage both source rows (coalesced 256B each)
            flds[wid][0][lane] = feats[s0 * INC + lane];
            flds[wid][1][lane] = feats[s1 * INC + lane];
            asm volatile("s_waitcnt lgkmcnt(0)" ::: "memory");  // cross-lane LDS visibility (lockstep wave)

            if (half < 2 && (half == 0 || has1)) {
                const float* fp = flds[wid][half];
                float4 a = make_float4(0.f, 0.f, 0.f, 0.f);
                #pragma unroll 8
                for (int i = 0; i < INC; ++i) {
                    float fi = fp[i];                                  // broadcast read
                    float4 w = *(const float4*)&Wlds[i * OUTC + cq];   // b128, ~conflict-free
                    a.x = fmaf(fi, w.x, a.x);
                    a.y = fmaf(fi, w.y, a.y);
                    a.z = fmaf(fi, w.z, a.z);
                    a.w = fmaf(fi, w.w, a.w);
                }
                const int r = half ? lr[e1] : lr[e];
                float4* ap = (float4*)&acc[r * OUTC + cq];   // unique (r,cq) per lane -> no race
                float4 cur = *ap;
                cur.x += a.x; cur.y += a.y; cur.z += a.z; cur.w += a.w;
                *ap = cur;
            }
        }
    }
    __syncthreads();

    // BN partial stats for this tile (96 channels)
    if (t < OUTC) {
        float s = 0.f, q = 0.f;
        int rmax = min(ROWS, N_VOX - base);
        for (int r = 0; r < rmax; ++r) {
            float v = acc[r * OUTC + t];
            s += v;
            q = fmaf(v, v, q);
        }
        atomicAdd(&stats[t], s);
        atomicAdd(&stats[OUTC + t], q);
    }

    // store conv output (d_out doubles as staging buffer)
    const long lim = (long)min(ROWS, N_VOX - base) * OUTC;
    for (long i = t; i < lim; i += 256) {
        out[(long)base * OUTC + i] = acc[i];
    }
}

__global__ void finalize_kernel(const float* __restrict__ gamma,
                                const float* __restrict__ beta,
                                float* __restrict__ stats) {
    int c = threadIdx.x;
    if (c < OUTC) {
        float inv_n = 1.0f / (float)N_VOX;
        float mean = stats[c] * inv_n;
        float var  = stats[OUTC + c] * inv_n - mean * mean;
        float sc   = gamma[c] * rsqrtf(var + EPSV);
        stats[2 * OUTC + c] = sc;
        stats[3 * OUTC + c] = beta[c] - mean * sc;
    }
}

__global__ void apply_bn_kernel(float* __restrict__ out,
                                const float* __restrict__ stats) {
    __shared__ float sc[OUTC], sh[OUTC];
    int t = threadIdx.x;
    if (t < OUTC) { sc[t] = stats[2 * OUTC + t]; sh[t] = stats[3 * OUTC + t]; }
    __syncthreads();
    const int total4 = N_VOX * OUTC / 4;
    for (int i = blockIdx.x * blockDim.x + t; i < total4; i += gridDim.x * blockDim.x) {
        float4 v = ((float4*)out)[i];
        int c = (i * 4) % OUTC;
        v.x = fmaxf(fmaf(v.x, sc[c    ], sh[c    ]), 0.f);
        v.y = fmaxf(fmaf(v.y, sc[c + 1], sh[c + 1]), 0.f);
        v.z = fmaxf(fmaf(v.z, sc[c + 2], sh[c + 2]), 0.f);
        v.w = fmaxf(fmaf(v.w, sc[c + 3], sh[c + 3]), 0.f);
        ((float4*)out)[i] = v;
    }
}

extern "C" void kernel_launch(void* const* d_in, const int* in_sizes, int n_in,
                              void* d_out, int out_size, void* d_ws, size_t ws_size,
                              hipStream_t stream) {
    const float* feats  = (const float*)d_in[0];
    const float* Wc     = (const float*)d_in[1];
    const float* Woff   = (const float*)d_in[2];
    const float* gamma  = (const float*)d_in[3];
    const float* beta   = (const float*)d_in[4];
    const int*   in_idx = (const int*)d_in[5];
    const int*   out_idx= (const int*)d_in[6];
    const int P = in_sizes[5] / NOFF;

    int*   srcmap = (int*)d_ws;                                       // 26*N ints = 20.8 MB
    float* stats  = (float*)((char*)d_ws + (size_t)NOFF * N_VOX * 4); // sums/sumsq/scale/shift
    float* out    = (float*)d_out;

    init_ws_kernel<<<2048, 256, 0, stream>>>(srcmap, stats);

    const int fill_total = NOFF * P;
    fill_src_kernel<<<(fill_total + 255) / 256, 256, 0, stream>>>(in_idx, out_idx, P, srcmap);

    conv_kernel<<<(N_VOX + ROWS - 1) / ROWS, 256, 0, stream>>>(feats, Wc, Woff, srcmap, out, stats);

    finalize_kernel<<<1, 128, 0, stream>>>(gamma, beta, stats);

    apply_bn_kernel<<<2048, 256, 0, stream>>>(out, stats);
}

// Round 2
// 189.902 us; speedup vs baseline: 3.2027x; 3.2027x over previous
//
#include <hip/hip_runtime.h>

// Sparse deconv (27-tap, 64->96ch) + BN + ReLU on MI355X, MFMA edition.
//
// srcmap inversion (out_idx unique per offset) -> dense per-offset gather.
// conv: 1 wave = 16 output rows x 96 cols = 6x mfma_f32_16x16x32_bf16 acc,
//       27 offsets, A = gathered bf16 feature rows, B = LDS-staged weights
//       (double-buffered, T14 issue-early/write-late). BN partial stats per
//       block -> ws, reduced by a 96-block kernel, applied fused with ReLU.

#define N_VOX   200000
#define INC     64
#define OUTC    96
#define NOFF    26
#define NBLOCKS 3125          // 200000 / 64 rows per block, exact
#define EPSV    1e-5f

using bf16x8 = __attribute__((ext_vector_type(8))) short;
using f32x4  = __attribute__((ext_vector_type(4))) float;

__device__ inline unsigned short f2bf(float x) {
    union { float f; unsigned u; } v; v.f = x;
    unsigned r = (v.u + 0x7FFFu + ((v.u >> 16) & 1u)) >> 16;
    return (unsigned short)r;
}

__global__ void init_ws_kernel(int* __restrict__ srcmap) {
    int idx = blockIdx.x * blockDim.x + threadIdx.x;
    int stride = gridDim.x * blockDim.x;
    for (int i = idx; i < NOFF * N_VOX; i += stride) srcmap[i] = -1;
}

__global__ void fill_src_kernel(const int* __restrict__ in_idx,
                                const int* __restrict__ out_idx,
                                int P, int* __restrict__ srcmap) {
    int idx = blockIdx.x * blockDim.x + threadIdx.x;
    if (idx >= NOFF * P) return;
    int dst = out_idx[idx];
    if (dst >= N_VOX) return;            // padded sink entries
    int k = idx / P;
    srcmap[(size_t)k * N_VOX + dst] = in_idx[idx];
}

// Weights -> bf16, pre-swizzled into B-fragment order:
// Wb[m][s][ct][lane][e] with k = s*32 + (lane>>4)*8 + e, col = ct*16 + (lane&15).
__global__ void wprep_kernel(const float* __restrict__ Wc,
                             const float* __restrict__ Woff,
                             unsigned short* __restrict__ Wb) {
    int t = blockIdx.x * blockDim.x + threadIdx.x;
    if (t >= 27 * 2 * 6 * 64) return;
    int lane = t & 63;
    int g    = t >> 6;              // m*12 + s*6 + ct
    int ct   = g % 6;
    int s    = (g / 6) % 2;
    int m    = g / 12;
    const float* W = (m == 26) ? Wc : (Woff + (size_t)m * INC * OUTC);
    int k0 = s * 32 + (lane >> 4) * 8;
    int c  = ct * 16 + (lane & 15);
    bf16x8 v;
    #pragma unroll
    for (int e = 0; e < 8; ++e)
        v[e] = (short)f2bf(W[(size_t)(k0 + e) * OUTC + c]);
    *(bf16x8*)(Wb + (size_t)t * 8) = v;
}

__global__ void fcvt_kernel(const float* __restrict__ feats,
                            unsigned short* __restrict__ featsb) {
    int i = blockIdx.x * blockDim.x + threadIdx.x;   // one per 8 elems
    if (i >= N_VOX * INC / 8) return;
    const float4* src = (const float4*)feats + (size_t)i * 2;
    float4 f0 = src[0], f1 = src[1];
    bf16x8 v;
    v[0] = (short)f2bf(f0.x); v[1] = (short)f2bf(f0.y);
    v[2] = (short)f2bf(f0.z); v[3] = (short)f2bf(f0.w);
    v[4] = (short)f2bf(f1.x); v[5] = (short)f2bf(f1.y);
    v[6] = (short)f2bf(f1.z); v[7] = (short)f2bf(f1.w);
    *(bf16x8*)(featsb + (size_t)i * 8) = v;
}

template<int BF16F>
__global__ __launch_bounds__(256, 4)
void conv_mfma_kernel(const float* __restrict__ feats,
                      const unsigned short* __restrict__ featsb,
                      const unsigned short* __restrict__ Wb,
                      const int* __restrict__ srcmap,
                      float* __restrict__ out,
                      float* __restrict__ pstats) {
    __shared__ __align__(16) unsigned short Wlds[2][6144];   // 2 x 12 KB

    const int t     = threadIdx.x;
    const int wid   = t >> 6;
    const int lane  = t & 63;
    const int blk   = blockIdx.x;
    const int rbase = blk * 64 + wid * 16;   // this wave's 16 output rows
    const int row16 = lane & 15;
    const int kgrp  = lane >> 4;             // 0..3

    f32x4 acc[6] = {};

    // prologue: stage weights for m=0 into buf 0
    {
        const uint4* ws = (const uint4*)Wb;
        uint4 w0 = ws[t], w1 = ws[256 + t], w2 = ws[512 + t];
        uint4* wd = (uint4*)Wlds[0];
        wd[t] = w0; wd[256 + t] = w1; wd[512 + t] = w2;
    }
    __syncthreads();

    for (int m = 0; m < 27; ++m) {
        // T14: issue next-offset weight loads early, write to LDS late
        uint4 w0, w1, w2;
        if (m < 26) {
            const uint4* ws = (const uint4*)(Wb + (size_t)(m + 1) * 6144);
            w0 = ws[t]; w1 = ws[256 + t]; w2 = ws[512 + t];
        }

        // source row for this wave's 16 output rows under offset m
        int src;
        if (m == 26) {
            src = rbase + row16;                       // center tap: identity
        } else {
            int sv = (lane < 16) ? srcmap[(size_t)m * N_VOX + rbase + lane] : -1;
            src = __shfl(sv, row16);
        }

        if (__ballot(src >= 0)) {
            bf16x8 a0 = {}, a1 = {};
            if (src >= 0) {
                if (BF16F) {
                    const unsigned short* fr = featsb + (size_t)src * INC;
                    a0 = *(const bf16x8*)(fr + kgrp * 8);        // k-step 0
                    a1 = *(const bf16x8*)(fr + 32 + kgrp * 8);   // k-step 1
                } else {
                    const float* fr = feats + (size_t)src * INC + kgrp * 8;
                    float4 f0 = *(const float4*)fr;
                    float4 f1 = *(const float4*)(fr + 4);
                    float4 f2 = *(const float4*)(fr + 32);
                    float4 f3 = *(const float4*)(fr + 36);
                    a0[0] = (short)f2bf(f0.x); a0[1] = (short)f2bf(f0.y);
                    a0[2] = (short)f2bf(f0.z); a0[3] = (short)f2bf(f0.w);
                    a0[4] = (short)f2bf(f1.x); a0[5] = (short)f2bf(f1.y);
                    a0[6] = (short)f2bf(f1.z); a0[7] = (short)f2bf(f1.w);
                    a1[0] = (short)f2bf(f2.x); a1[1] = (short)f2bf(f2.y);
                    a1[2] = (short)f2bf(f2.z); a1[3] = (short)f2bf(f2.w);
                    a1[4] = (short)f2bf(f3.x); a1[5] = (short)f2bf(f3.y);
                    a1[6] = (short)f2bf(f3.z); a1[7] = (short)f2bf(f3.w);
                }
            }
            const unsigned short* WL = Wlds[m & 1];
            #pragma unroll
            for (int ct = 0; ct < 6; ++ct) {
                bf16x8 b0 = *(const bf16x8*)&WL[(size_t)ct * 512 + lane * 8];
                bf16x8 b1 = *(const bf16x8*)&WL[(size_t)(6 + ct) * 512 + lane * 8];
                acc[ct] = __builtin_amdgcn_mfma_f32_16x16x32_bf16(a0, b0, acc[ct], 0, 0, 0);
                acc[ct] = __builtin_amdgcn_mfma_f32_16x16x32_bf16(a1, b1, acc[ct], 0, 0, 0);
            }
        }

        if (m < 26) {
            uint4* wd = (uint4*)Wlds[(m + 1) & 1];
            wd[t] = w0; wd[256 + t] = w1; wd[512 + t] = w2;
        }
        __syncthreads();
    }

    // ---- BN partial stats: per-lane -> wave shfl reduce -> LDS cross-wave ----
    float s6[6], q6[6];
    #pragma unroll
    for (int ct = 0; ct < 6; ++ct) {
        f32x4 a = acc[ct];
        float s = a[0] + a[1] + a[2] + a[3];
        float q = a[0]*a[0] + a[1]*a[1] + a[2]*a[2] + a[3]*a[3];
        s += __shfl_xor(s, 16); q += __shfl_xor(q, 16);
        s += __shfl_xor(s, 32); q += __shfl_xor(q, 32);
        s6[ct] = s; q6[ct] = q;
    }
    float* sred = (float*)Wlds;      // reuse LDS (post loop-final barrier)
    if (lane < 16) {
        #pragma unroll
        for (int ct = 0; ct < 6; ++ct) {
            sred[wid * 96 + ct * 16 + lane]       = s6[ct];
            sred[384 + wid * 96 + ct * 16 + lane] = q6[ct];
        }
    }
    __syncthreads();
    if (t < 96) {
        float s = sred[t] + sred[96 + t] + sred[192 + t] + sred[288 + t];
        pstats[(size_t)t * NBLOCKS + blk] = s;
    } else if (t < 192) {
        int c = t - 96;
        float q = sred[384 + c] + sred[480 + c] + sred[576 + c] + sred[672 + c];
        pstats[(size_t)(96 + c) * NBLOCKS + blk] = q;
    }

    // ---- store conv output (fp32 staging in d_out) ----
    #pragma unroll
    for (int ct = 0; ct < 6; ++ct) {
        #pragma unroll
        for (int j = 0; j < 4; ++j) {
            out[(size_t)(rbase + kgrp * 4 + j) * OUTC + ct * 16 + row16] = acc[ct][j];
        }
    }
}

__global__ void stats_reduce_kernel(const float* __restrict__ pstats,
                                    const float* __restrict__ gamma,
                                    const float* __restrict__ beta,
                                    float* __restrict__ scsh) {
    int c = blockIdx.x;               // 0..95
    int t = threadIdx.x;
    float s = 0.f, q = 0.f;
    for (int i = t; i < NBLOCKS; i += 256) {
        s += pstats[(size_t)c * NBLOCKS + i];
        q += pstats[(size_t)(96 + c) * NBLOCKS + i];
    }
    #pragma unroll
    for (int d = 1; d < 64; d <<= 1) {
        s += __shfl_xor(s, d);
        q += __shfl_xor(q, d);
    }
    __shared__ float rs[4], rq[4];
    if ((t & 63) == 0) { rs[t >> 6] = s; rq[t >> 6] = q; }
    __syncthreads();
    if (t == 0) {
        s = rs[0] + rs[1] + rs[2] + rs[3];
        q = rq[0] + rq[1] + rq[2] + rq[3];
        float inv_n = 1.0f / (float)N_VOX;
        float mean = s * inv_n;
        float var  = q * inv_n - mean * mean;
        float sc   = gamma[c] * rsqrtf(var + EPSV);
        scsh[c]      = sc;
        scsh[96 + c] = beta[c] - mean * sc;
    }
}

__global__ void apply_bn_kernel(float* __restrict__ out,
                                const float* __restrict__ scsh) {
    __shared__ float sc[OUTC], sh[OUTC];
    int t = threadIdx.x;
    if (t < OUTC) { sc[t] = scsh[t]; sh[t] = scsh[96 + t]; }
    __syncthreads();
    const int total4 = N_VOX * OUTC / 4;
    for (int i = blockIdx.x * blockDim.x + t; i < total4; i += gridDim.x * blockDim.x) {
        float4 v = ((float4*)out)[i];
        int c = (i * 4) % OUTC;
        v.x = fmaxf(fmaf(v.x, sc[c    ], sh[c    ]), 0.f);
        v.y = fmaxf(fmaf(v.y, sc[c + 1], sh[c + 1]), 0.f);
        v.z = fmaxf(fmaf(v.z, sc[c + 2], sh[c + 2]), 0.f);
        v.w = fmaxf(fmaf(v.w, sc[c + 3], sh[c + 3]), 0.f);
        ((float4*)out)[i] = v;
    }
}

extern "C" void kernel_launch(void* const* d_in, const int* in_sizes, int n_in,
                              void* d_out, int out_size, void* d_ws, size_t ws_size,
                              hipStream_t stream) {
    const float* feats   = (const float*)d_in[0];
    const float* Wc      = (const float*)d_in[1];
    const float* Woff    = (const float*)d_in[2];
    const float* gamma   = (const float*)d_in[3];
    const float* beta    = (const float*)d_in[4];
    const int*   in_idx  = (const int*)d_in[5];
    const int*   out_idx = (const int*)d_in[6];
    const int P = in_sizes[5] / NOFF;

    char* w = (char*)d_ws;
    int* srcmap = (int*)w;                 w += (size_t)NOFF * N_VOX * 4;   // 20.8 MB
    unsigned short* Wb = (unsigned short*)w; w += (size_t)27 * 6144 * 2;    // 331 KB
    float* pstats = (float*)w;             w += (size_t)192 * NBLOCKS * 4;  // 2.4 MB
    float* scsh = (float*)w;               w += 256 * 4;
    unsigned short* featsb = (unsigned short*)w;
    size_t need_bf16 = (size_t)(w - (char*)d_ws) + (size_t)N_VOX * INC * 2; // +25.6 MB
    bool bf16f = (ws_size >= need_bf16);

    init_ws_kernel<<<1024, 256, 0, stream>>>(srcmap);
    fill_src_kernel<<<(NOFF * P + 255) / 256, 256, 0, stream>>>(in_idx, out_idx, P, srcmap);
    wprep_kernel<<<(27 * 2 * 6 * 64 + 255) / 256, 256, 0, stream>>>(Wc, Woff, Wb);

    float* out = (float*)d_out;
    if (bf16f) {
        fcvt_kernel<<<(N_VOX * INC / 8 + 255) / 256, 256, 0, stream>>>(feats, featsb);
        conv_mfma_kernel<1><<<NBLOCKS, 256, 0, stream>>>(feats, featsb, Wb, srcmap, out, pstats);
    } else {
        conv_mfma_kernel<0><<<NBLOCKS, 256, 0, stream>>>(feats, featsb, Wb, srcmap, out, pstats);
    }
    stats_reduce_kernel<<<96, 256, 0, stream>>>(pstats, gamma, beta, scsh);
    apply_bn_kernel<<<2048, 256, 0, stream>>>(out, scsh);
}

// Round 3
// 130.285 us; speedup vs baseline: 4.6682x; 1.4576x over previous
//
#include <hip/hip_runtime.h>

// Sparse deconv (27-tap, 64->96ch) + BN + ReLU on MI355X.
// M=64 rows/wave MFMA (amortize B LDS reads over 48 MFMAs), 2-deep srcmap
// prefetch + 1-deep gather prefetch + global_load_lds B double-buffer.

#define N_VOX   200000
#define INC     64
#define OUTC    96
#define NOFF    26
#define NBLK    782           // ceil(200000 / 256)
#define EPSV    1e-5f

using bf16x8 = __attribute__((ext_vector_type(8))) short;
using f32x4  = __attribute__((ext_vector_type(4))) float;

__device__ inline unsigned short f2bf(float x) {
    union { float f; unsigned u; } v; v.f = x;
    unsigned r = (v.u + 0x7FFFu + ((v.u >> 16) & 1u)) >> 16;
    return (unsigned short)r;
}

__device__ __forceinline__ void gload_lds16(const void* g, void* l) {
    __builtin_amdgcn_global_load_lds(
        (const __attribute__((address_space(1))) void*)g,
        (__attribute__((address_space(3))) void*)l, 16, 0, 0);
}

__global__ void fill_src_kernel(const int* __restrict__ in_idx,
                                const int* __restrict__ out_idx,
                                int P, int* __restrict__ srcmap) {
    int idx = blockIdx.x * blockDim.x + threadIdx.x;
    if (idx >= NOFF * P) return;
    int dst = out_idx[idx];
    if (dst >= N_VOX) return;            // padded sink entries
    int k = idx / P;
    srcmap[(size_t)k * N_VOX + dst] = in_idx[idx];
}

// Weights -> bf16, B-fragment order: Wb[m][s][ct][lane][e],
// k = s*32 + (lane>>4)*8 + e, col = ct*16 + (lane&15).
__global__ void wprep_kernel(const float* __restrict__ Wc,
                             const float* __restrict__ Woff,
                             unsigned short* __restrict__ Wb) {
    int t = blockIdx.x * blockDim.x + threadIdx.x;
    if (t >= 27 * 2 * 6 * 64) return;
    int lane = t & 63;
    int g    = t >> 6;              // m*12 + s*6 + ct
    int ct   = g % 6;
    int s    = (g / 6) % 2;
    int m    = g / 12;
    const float* W = (m == 26) ? Wc : (Woff + (size_t)m * INC * OUTC);
    int k0 = s * 32 + (lane >> 4) * 8;
    int c  = ct * 16 + (lane & 15);
    bf16x8 v;
    #pragma unroll
    for (int e = 0; e < 8; ++e)
        v[e] = (short)f2bf(W[(size_t)(k0 + e) * OUTC + c]);
    *(bf16x8*)(Wb + (size_t)t * 8) = v;
}

__global__ void fcvt_kernel(const float* __restrict__ feats,
                            unsigned short* __restrict__ featsb) {
    int i = blockIdx.x * blockDim.x + threadIdx.x;   // one per 8 elems
    if (i >= N_VOX * INC / 8) return;
    const float4* src = (const float4*)feats + (size_t)i * 2;
    float4 f0 = src[0], f1 = src[1];
    bf16x8 v;
    v[0] = (short)f2bf(f0.x); v[1] = (short)f2bf(f0.y);
    v[2] = (short)f2bf(f0.z); v[3] = (short)f2bf(f0.w);
    v[4] = (short)f2bf(f1.x); v[5] = (short)f2bf(f1.y);
    v[6] = (short)f2bf(f1.z); v[7] = (short)f2bf(f1.w);
    *(bf16x8*)(featsb + (size_t)i * 8) = v;
}

// tap order: idx 0 -> center (26), idx i>=1 -> offset i-1.
__global__ __launch_bounds__(256, 2)
void conv_mfma_kernel(const unsigned short* __restrict__ featsb,
                      const unsigned short* __restrict__ Wb,
                      const int* __restrict__ srcmap,
                      float* __restrict__ out,
                      float* __restrict__ pstats) {
    __shared__ __align__(16) unsigned short Wlds[2][6144];   // 2 x 12 KB

    const int t     = threadIdx.x;
    const int wid   = t >> 6;
    const int lane  = t & 63;
    const int blk   = blockIdx.x;
    const int rbase = blk * 256 + wid * 64;   // this wave's 64 output rows
    const int row16 = lane & 15;
    const int kgrp  = lane >> 4;              // 0..3

    f32x4  acc[4][6] = {};
    bf16x8 aC[4][2] = {}, aN[4][2] = {};

    // ---- prologue ----
    // stage B for center tap into buf 0
    #pragma unroll
    for (int i = 0; i < 3; ++i)
        gload_lds16(Wb + (size_t)26 * 6144 + (size_t)(t + 256 * i) * 8,
                    &Wlds[0][(t + 256 * i) * 8]);

    // srcmap prefetch for tap 0 (consumed at idx=0 to gather for idx=1)
    int sm_next = -1;
    {
        int row = rbase + lane;
        if (row < N_VOX) sm_next = srcmap[row];          // offset 0
    }
    // gather center rows -> aC (identity src)
    bool has_cur = false;
    #pragma unroll
    for (int rt = 0; rt < 4; ++rt) {
        int src = rbase + rt * 16 + row16;
        if (src < N_VOX) {
            const unsigned short* fr = featsb + (size_t)src * INC + kgrp * 8;
            aC[rt][0] = *(const bf16x8*)fr;
            aC[rt][1] = *(const bf16x8*)(fr + 32);
            has_cur = true;
        }
    }
    has_cur = __ballot(has_cur) != 0ull;
    __syncthreads();

    for (int idx = 0; idx < 27; ++idx) {
        const int buf = idx & 1;

        // 1. srcmap prefetch, 2 taps ahead (offset idx+1)
        int sm_next2 = -1;
        if (idx <= 24) {
            int row = rbase + lane;
            if (row < N_VOX) sm_next2 = srcmap[(size_t)(idx + 1) * N_VOX + row];
        }

        // 2. gather A for next tap (offset idx) + stage its B into buf^1
        bool has_next = false;
        if (idx <= 25) {
            bool any = false;
            #pragma unroll
            for (int rt = 0; rt < 4; ++rt) {
                int src = __shfl(sm_next, rt * 16 + row16);
                bf16x8 g0 = {}, g1 = {};
                if (src >= 0) {
                    const unsigned short* fr = featsb + (size_t)src * INC + kgrp * 8;
                    g0 = *(const bf16x8*)fr;
                    g1 = *(const bf16x8*)(fr + 32);
                    any = true;
                }
                aN[rt][0] = g0; aN[rt][1] = g1;
            }
            has_next = __ballot(any) != 0ull;
            #pragma unroll
            for (int i = 0; i < 3; ++i)
                gload_lds16(Wb + (size_t)idx * 6144 + (size_t)(t + 256 * i) * 8,
                            &Wlds[buf ^ 1][(t + 256 * i) * 8]);
        }

        // 3. MFMA current tap
        if (has_cur) {
            const unsigned short* WL = Wlds[buf];
            #pragma unroll
            for (int ct = 0; ct < 6; ++ct) {
                bf16x8 b0 = *(const bf16x8*)&WL[(size_t)ct * 512 + lane * 8];
                bf16x8 b1 = *(const bf16x8*)&WL[(size_t)(6 + ct) * 512 + lane * 8];
                #pragma unroll
                for (int rt = 0; rt < 4; ++rt) {
                    acc[rt][ct] = __builtin_amdgcn_mfma_f32_16x16x32_bf16(aC[rt][0], b0, acc[rt][ct], 0, 0, 0);
                    acc[rt][ct] = __builtin_amdgcn_mfma_f32_16x16x32_bf16(aC[rt][1], b1, acc[rt][ct], 0, 0, 0);
                }
            }
        }
        __syncthreads();

        #pragma unroll
        for (int rt = 0; rt < 4; ++rt) { aC[rt][0] = aN[rt][0]; aC[rt][1] = aN[rt][1]; }
        sm_next = sm_next2;
        has_cur = has_next;
    }

    // ---- BN partial stats: lane -> wave shfl -> LDS cross-wave ----
    float s6[6], q6[6];
    #pragma unroll
    for (int ct = 0; ct < 6; ++ct) {
        float s = 0.f, q = 0.f;
        #pragma unroll
        for (int rt = 0; rt < 4; ++rt) {
            f32x4 a = acc[rt][ct];
            s += a[0] + a[1] + a[2] + a[3];
            q += a[0]*a[0] + a[1]*a[1] + a[2]*a[2] + a[3]*a[3];
        }
        s += __shfl_xor(s, 16); q += __shfl_xor(q, 16);
        s += __shfl_xor(s, 32); q += __shfl_xor(q, 32);
        s6[ct] = s; q6[ct] = q;
    }
    float* sred = (float*)Wlds;      // reuse LDS (post final barrier)
    if (lane < 16) {
        #pragma unroll
        for (int ct = 0; ct < 6; ++ct) {
            sred[wid * 96 + ct * 16 + lane]       = s6[ct];
            sred[384 + wid * 96 + ct * 16 + lane] = q6[ct];
        }
    }
    __syncthreads();
    if (t < 96) {
        float s = sred[t] + sred[96 + t] + sred[192 + t] + sred[288 + t];
        pstats[(size_t)t * NBLK + blk] = s;
    } else if (t < 192) {
        int c = t - 96;
        float q = sred[384 + c] + sred[480 + c] + sred[576 + c] + sred[672 + c];
        pstats[(size_t)(96 + c) * NBLK + blk] = q;
    }

    // ---- store conv output (fp32 staging in d_out) ----
    #pragma unroll
    for (int rt = 0; rt < 4; ++rt) {
        #pragma unroll
        for (int ct = 0; ct < 6; ++ct) {
            #pragma unroll
            for (int j = 0; j < 4; ++j) {
                int row = rbase + rt * 16 + kgrp * 4 + j;
                if (row < N_VOX)
                    out[(size_t)row * OUTC + ct * 16 + row16] = acc[rt][ct][j];
            }
        }
    }
}

__global__ void stats_reduce_kernel(const float* __restrict__ pstats,
                                    const float* __restrict__ gamma,
                                    const float* __restrict__ beta,
                                    float* __restrict__ scsh) {
    int c = blockIdx.x;               // 0..95
    int t = threadIdx.x;
    float s = 0.f, q = 0.f;
    for (int i = t; i < NBLK; i += 256) {
        s += pstats[(size_t)c * NBLK + i];
        q += pstats[(size_t)(96 + c) * NBLK + i];
    }
    #pragma unroll
    for (int d = 1; d < 64; d <<= 1) {
        s += __shfl_xor(s, d);
        q += __shfl_xor(q, d);
    }
    __shared__ float rs[4], rq[4];
    if ((t & 63) == 0) { rs[t >> 6] = s; rq[t >> 6] = q; }
    __syncthreads();
    if (t == 0) {
        s = rs[0] + rs[1] + rs[2] + rs[3];
        q = rq[0] + rq[1] + rq[2] + rq[3];
        float inv_n = 1.0f / (float)N_VOX;
        float mean = s * inv_n;
        float var  = q * inv_n - mean * mean;
        float sc   = gamma[c] * rsqrtf(var + EPSV);
        scsh[c]      = sc;
        scsh[96 + c] = beta[c] - mean * sc;
    }
}

__global__ void apply_bn_kernel(float* __restrict__ out,
                                const float* __restrict__ scsh) {
    __shared__ float sc[OUTC], sh[OUTC];
    int t = threadIdx.x;
    if (t < OUTC) { sc[t] = scsh[t]; sh[t] = scsh[96 + t]; }
    __syncthreads();
    const int total4 = N_VOX * OUTC / 4;
    for (int i = blockIdx.x * blockDim.x + t; i < total4; i += gridDim.x * blockDim.x) {
        float4 v = ((float4*)out)[i];
        int c = (i * 4) % OUTC;
        v.x = fmaxf(fmaf(v.x, sc[c    ], sh[c    ]), 0.f);
        v.y = fmaxf(fmaf(v.y, sc[c + 1], sh[c + 1]), 0.f);
        v.z = fmaxf(fmaf(v.z, sc[c + 2], sh[c + 2]), 0.f);
        v.w = fmaxf(fmaf(v.w, sc[c + 3], sh[c + 3]), 0.f);
        ((float4*)out)[i] = v;
    }
}

extern "C" void kernel_launch(void* const* d_in, const int* in_sizes, int n_in,
                              void* d_out, int out_size, void* d_ws, size_t ws_size,
                              hipStream_t stream) {
    const float* feats   = (const float*)d_in[0];
    const float* Wc      = (const float*)d_in[1];
    const float* Woff    = (const float*)d_in[2];
    const float* gamma   = (const float*)d_in[3];
    const float* beta    = (const float*)d_in[4];
    const int*   in_idx  = (const int*)d_in[5];
    const int*   out_idx = (const int*)d_in[6];
    const int P = in_sizes[5] / NOFF;

    char* w = (char*)d_ws;
    int* srcmap = (int*)w;                   w += (size_t)NOFF * N_VOX * 4;   // 20.8 MB
    unsigned short* Wb = (unsigned short*)w; w += (size_t)27 * 6144 * 2;      // 331 KB
    float* pstats = (float*)w;               w += (size_t)192 * NBLK * 4;     // 0.6 MB
    float* scsh = (float*)w;                 w += 256 * 4;
    unsigned short* featsb = (unsigned short*)w;                              // 25.6 MB

    hipMemsetAsync(srcmap, 0xFF, (size_t)NOFF * N_VOX * 4, stream);
    fill_src_kernel<<<(NOFF * P + 255) / 256, 256, 0, stream>>>(in_idx, out_idx, P, srcmap);
    wprep_kernel<<<(27 * 2 * 6 * 64 + 255) / 256, 256, 0, stream>>>(Wc, Woff, Wb);
    fcvt_kernel<<<(N_VOX * INC / 8 + 255) / 256, 256, 0, stream>>>(feats, featsb);

    float* out = (float*)d_out;
    conv_mfma_kernel<<<NBLK, 256, 0, stream>>>(featsb, Wb, srcmap, out, pstats);
    stats_reduce_kernel<<<96, 256, 0, stream>>>(pstats, gamma, beta, scsh);
    apply_bn_kernel<<<2048, 256, 0, stream>>>(out, scsh);
}